// Round 1
// 672.231 us; speedup vs baseline: 1.0036x; 1.0036x over previous
//
#include <hip/hip_runtime.h>

// Greedy CTC decode: T=1048576 rows, V=128 labels (512 B/row), blank=0.
// Outputs concatenated float32 in d_out: [idx | keep(0/1) | path_score].
//
// 8 lanes/row. Changes vs previous version:
//  - boundary row (base-1) is consumed BEFORE the main loop so its 16 VGPRs
//    die immediately (was live across the whole unrolled loop -> spill risk)
//  - local argmax is a depth-4 tournament tree (was a 15-deep serial chain)
//  - cross-lane reduce uses DPP (quad_perm xor1/xor2 + row_half_mirror=xor7)
//    instead of 6 ds_swizzle ops per iteration: no LDS pipe, ~8 cy/round
//  - __launch_bounds__(256,8): target 8 waves/SIMD (32 waves/CU), <=64 VGPR
// Block = 256 thr = 4 waves = 256 rows; register double-buffer retained.

#define VLAB 128
#define RPB 256

// winner of a float4 chunk, columns cbase..cbase+3, first-max-wins (strict >)
__device__ __forceinline__ void chunk_amax(float4 q, int cbase, float& v, int& c) {
    float va = q.x; int ca = cbase;
    if (q.y > va) { va = q.y; ca = cbase + 1; }
    float vb = q.z; int cb = cbase + 2;
    if (q.w > vb) { vb = q.w; cb = cbase + 3; }
    v = va; c = ca;
    if (vb > va) { v = vb; c = cb; }
}

// lane-local argmax of 16 elems; pairs always (lowerCols, higherCols) with
// strict > so ties resolve to the lowest column (jnp.argmax semantics).
__device__ __forceinline__ void argmax16(const float4 q[4], int g, float& bv, int& bi) {
    const int c0 = g << 2;
    float v0, v1, v2, v3; int i0, i1, i2, i3;
    chunk_amax(q[0], c0,      v0, i0);
    chunk_amax(q[1], c0 + 32, v1, i1);
    chunk_amax(q[2], c0 + 64, v2, i2);
    chunk_amax(q[3], c0 + 96, v3, i3);
    if (v1 > v0) { v0 = v1; i0 = i1; }
    if (v3 > v2) { v2 = v3; i2 = i3; }
    bv = v0; bi = i0;
    if (v2 > v0) { bv = v2; bi = i2; }
}

// one DPP reduce round: combine with lane^k partner, tie -> lower index
template <int CTRL>
__device__ __forceinline__ void dpp_red(float& bv, int& bi) {
    const int ovb = __builtin_amdgcn_update_dpp(0, __float_as_int(bv), CTRL, 0xF, 0xF, true);
    const int oib = __builtin_amdgcn_update_dpp(0, bi, CTRL, 0xF, 0xF, true);
    const float ov = __int_as_float(ovb);
    if (ov > bv || (ov == bv && oib < bi)) { bv = ov; bi = oib; }
}

__device__ __forceinline__ void group8_reduce(float& bv, int& bi) {
    dpp_red<0xB1>(bv, bi);   // quad_perm [1,0,3,2] : xor 1
    dpp_red<0x4E>(bv, bi);   // quad_perm [2,3,0,1] : xor 2
    dpp_red<0x141>(bv, bi);  // row_half_mirror     : xor 7 within 8-lane group
}

__global__ __launch_bounds__(256, 8) void ctc_fused(const float4* __restrict__ em4,
                                                    float* __restrict__ out_idx,
                                                    float* __restrict__ out_keep,
                                                    float* __restrict__ out_score) {
    __shared__ int   s_idx[RPB + 1];
    __shared__ float s_max[RPB + 1];

    const int tid  = threadIdx.x;
    const int wave = tid >> 6;
    const int lane = tid & 63;
    const int g    = lane & 7;    // lane within 8-lane row group
    const int rsub = lane >> 3;   // row within wave-iteration (0..7)
    const int base = blockIdx.x * RPB;

    // Boundary row (base-1): issue loads first so they overlap the prologue.
    const bool do_bnd = (wave == 0) && (blockIdx.x > 0);
    float4 bb[4];
    if (do_bnd) {
        const float4* bp = em4 + (size_t)(base - 1) * 32 + g;
        bb[0] = bp[0]; bb[1] = bp[8]; bb[2] = bp[16]; bb[3] = bp[24];
    }

    // Prologue: issue iteration-0 loads (all waves) before touching bb.
    float4 buf[2][4];
    {
        const float4* rp = em4 + (size_t)(base + wave * 8 + rsub) * 32 + g;
        buf[0][0] = rp[0]; buf[0][1] = rp[8]; buf[0][2] = rp[16]; buf[0][3] = rp[24];
    }

    // Consume the boundary row NOW: bb's registers die before the main loop.
    // Wave 0 eats one load latency here; waves 1-3 and other blocks cover it.
    if (do_bnd) {
        float bv; int bi;
        argmax16(bb, g, bv, bi);
        group8_reduce(bv, bi);
        if (lane == 0) s_idx[0] = bi;
    } else if (blockIdx.x == 0 && tid == 0) {
        s_idx[0] = -1;  // prev of row 0
    }

    #pragma unroll
    for (int i = 0; i < 8; ++i) {
        const int cur = i & 1;
        if (i < 7) {
            const int nrow = base + (i + 1) * 32 + wave * 8 + rsub;
            const float4* rp = em4 + (size_t)nrow * 32 + g;
            buf[cur ^ 1][0] = rp[0];  buf[cur ^ 1][1] = rp[8];
            buf[cur ^ 1][2] = rp[16]; buf[cur ^ 1][3] = rp[24];
        }
        float bv; int bi;
        argmax16(buf[cur], g, bv, bi);
        group8_reduce(bv, bi);
        if (g == 0) {
            const int slot = i * 32 + wave * 8 + rsub + 1;
            s_idx[slot] = bi;
            s_max[slot] = bv;
        }
    }

    __syncthreads();

    // Coalesced epilogue: one row per thread.
    const int r   = base + tid;
    const int cur = s_idx[tid + 1];
    const int prv = s_idx[tid];
    const bool keep = (cur != prv) && (cur != 0);
    out_idx[r]   = (float)cur;
    out_keep[r]  = keep ? 1.0f : 0.0f;
    out_score[r] = keep ? s_max[tid + 1] : 0.0f;
}

extern "C" void kernel_launch(void* const* d_in, const int* in_sizes, int n_in,
                              void* d_out, int out_size, void* d_ws, size_t ws_size,
                              hipStream_t stream) {
    const float* em = (const float*)d_in[0];
    const int T = in_sizes[0] / VLAB;

    float* out       = (float*)d_out;
    float* out_idx   = out;
    float* out_keep  = out + (size_t)T;
    float* out_score = out + (size_t)2 * T;

    const int grid = T / RPB;  // 4096 blocks
    ctc_fused<<<grid, RPB, 0, stream>>>(
        reinterpret_cast<const float4*>(em), out_idx, out_keep, out_score);
}